// Round 7
// baseline (1439.597 us; speedup 1.0000x reference)
//
#include <hip/hip_runtime.h>
#include <cstddef>
#include <cstdint>

#define BATCH 32
#define SEQ 2048
#define DM 1024

typedef __attribute__((ext_vector_type(8))) _Float16 half8v;
typedef __attribute__((ext_vector_type(4))) _Float16 half4v;
typedef __attribute__((ext_vector_type(4))) float f32x4;

// Persistent device-global scratch (fully rewritten every launch; no stale-state deps)
__device__ _Float16 g_B16[DM * DM];            // Wk_w pre-converted to fp16 (2 MB)
__device__ float g_q[BATCH * DM];              // q projection (128 KB)
__device__ float g_sp[8][BATCH * SEQ];         // scores partials: slot = nchunk*2 + wn

// tanh(x) = 1 - 2/(e^{2x}+1); saturates to +-1 correctly for |x| large
__device__ __forceinline__ float tanh_fast(float x) {
    float e = __expf(2.0f * x);
    return 1.0f - 2.0f / (e + 1.0f);
}

__device__ __forceinline__ void gload16(const void* g, void* l) {
    __builtin_amdgcn_global_load_lds((__attribute__((address_space(1))) void*)g,
                                     (__attribute__((address_space(3))) void*)l, 16, 0, 0);
}

// ---------------- convert Wk_w -> fp16 (once per launch, ~6 MB traffic) ----------------
__global__ __launch_bounds__(256) void convb_kernel(const float* __restrict__ Wk_w) {
    int i = blockIdx.x * 256 + threadIdx.x;            // 262144 float4 groups
    float4 w = reinterpret_cast<const float4*>(Wk_w)[i];
    half4v h;
    h[0] = (_Float16)w.x; h[1] = (_Float16)w.y; h[2] = (_Float16)w.z; h[3] = (_Float16)w.w;
    *reinterpret_cast<half4v*>(&g_B16[(size_t)i * 4]) = h;
}

// ---------------- init: zero context (atomically accumulated) ----------------
__global__ __launch_bounds__(256) void init_kernel(float* __restrict__ context) {
    int idx = blockIdx.x * 256 + threadIdx.x;
    if (idx < BATCH * DM) context[idx] = 0.f;
}

// ---------------- q projection: block per output d; Wq read once total ----------------
__global__ __launch_bounds__(256) void qproj_kernel(const float* __restrict__ query,
                                                    const float* __restrict__ Wq_w,
                                                    const float* __restrict__ Wq_b) {
    int d = blockIdx.x;
    int t = threadIdx.x;
    __shared__ float wrow[DM];
    __shared__ float part[8][32];
    reinterpret_cast<float4*>(wrow)[t] =
        reinterpret_cast<const float4*>(Wq_w + (size_t)d * DM)[t];
    __syncthreads();
    int b = t & 31, seg = t >> 5;
    const float4* qp = reinterpret_cast<const float4*>(query + b * DM + seg * 128);
    const float4* wp = reinterpret_cast<const float4*>(wrow + seg * 128);
    float acc = 0.f;
#pragma unroll
    for (int i = 0; i < 32; ++i) {
        float4 qv = qp[i];
        float4 wv = wp[i];
        acc += qv.x * wv.x + qv.y * wv.y + qv.z * wv.z + qv.w * wv.w;
    }
    part[seg][b] = acc;
    __syncthreads();
    if (t < 32) {
        float s = Wq_b[d];
#pragma unroll
        for (int g = 0; g < 8; ++g) s += part[g][t];
        g_q[t * DM + d] = s;
    }
}

// ---------------- scores: single-pass fp16 MFMA GEMM, counted-vmcnt pipeline ----------
#define BM 128
#define BN 256
#define BK 32
#define NT (DM / BK)   // 32 K-steps

__global__ __launch_bounds__(256, 3) void scores_kernel(const float* __restrict__ keys,
                                                        const float* __restrict__ Wk_b,
                                                        const float* __restrict__ v_w) {
    // K-subtiled [buf][kc][row][8] fp16, 16B rows; B region layout matches the
    // linear lane x 16B pattern global_load_lds writes. Total 48 KB -> 3 blocks/CU.
    __shared__ _Float16 AhS[2][4][BM][8];   // 16 KB
    __shared__ _Float16 BhS[2][4][BN][8];   // 32 KB

    // XCD-aware order: 2048 blocks = 8 XCDs x 256 slots (bijective); nchunk-minor
    // so the 4 blocks sharing an A-tile are co-resident on one XCD (A read once).
    const unsigned bid = blockIdx.x;
    const unsigned L = (bid & 7u) * 256u + (bid >> 3);
    const int mtile = (int)(L >> 2);       // 0..511
    const int nchunk = (int)(L & 3u);      // 0..3
    const int m0 = mtile * BM;
    const int n0 = nchunk * BN;
    const int b = m0 >> 11;

    const int t = threadIdx.x;
    const int w = t >> 6, l = t & 63;
    const int wm = w >> 1, wn = w & 1;     // 2x2 waves; wave tile 64m x 128n
    const int lr = l & 15, lg = l >> 4;

    // A staging: 2 threads/row, 16 k-elems each.
    const int ra = t >> 1, ha = t & 1;
    const float* Ap = keys + (size_t)(m0 + ra) * DM + ha * 16;

    float4 asA[4], asB[4];   // two A staging sets (pipeline depth 2 tiles)

    f32x4 acc[4][8];
#pragma unroll
    for (int mi = 0; mi < 4; ++mi)
#pragma unroll
        for (int ni = 0; ni < 8; ++ni)
#pragma unroll
            for (int c = 0; c < 4; ++c) acc[mi][ni][c] = 0.f;

#define LOAD_A(dst, kt)                                                          \
    {                                                                            \
        _Pragma("unroll") for (int j = 0; j < 4; ++j)                            \
            dst[j] = *reinterpret_cast<const float4*>(Ap + (kt) * BK + 4 * j);   \
    }
    // wave w DMAs kc=w plane: 4 issues x 64 rows x 16B
#define ISSUE_B(kt, bufi)                                                        \
    {                                                                            \
        const _Float16* gb = &g_B16[(size_t)(n0 + l) * DM + (kt) * BK + w * 8];  \
        _Pragma("unroll") for (int rg = 0; rg < 4; ++rg)                         \
            gload16(gb + (size_t)rg * 64 * DM, &BhS[bufi][w][rg * 64][0]);       \
    }
#define STAGE_A(bufi, aset)                                                      \
    {                                                                            \
        union H8 { _Float16 f[8]; half8v v; } ah[2];                             \
        _Pragma("unroll") for (int j = 0; j < 4; ++j) {                          \
            const float* fa = reinterpret_cast<const float*>(&aset[j]);          \
            _Pragma("unroll") for (int c = 0; c < 4; ++c) {                      \
                int idx = 4 * j + c;                                             \
                ah[idx >> 3].f[idx & 7] = (_Float16)fa[c];                       \
            }                                                                    \
        }                                                                        \
        *reinterpret_cast<half8v*>(&AhS[bufi][2 * ha][ra][0]) = ah[0].v;         \
        *reinterpret_cast<half8v*>(&AhS[bufi][2 * ha + 1][ra][0]) = ah[1].v;     \
    }
#define COMPUTE(bufi)                                                            \
    {                                                                            \
        half8v bhv[8];                                                           \
        _Pragma("unroll") for (int ni = 0; ni < 8; ++ni)                         \
            bhv[ni] = *reinterpret_cast<const half8v*>(                          \
                &BhS[bufi][lg][wn * 128 + ni * 16 + lr][0]);                     \
        __builtin_amdgcn_s_setprio(1);                                           \
        _Pragma("unroll") for (int mi = 0; mi < 4; ++mi) {                       \
            half8v ahv = *reinterpret_cast<const half8v*>(                       \
                &AhS[bufi][lg][wm * 64 + mi * 16 + lr][0]);                      \
            _Pragma("unroll") for (int ni = 0; ni < 8; ++ni)                     \
                acc[mi][ni] = __builtin_amdgcn_mfma_f32_16x16x32_f16(            \
                    ahv, bhv[ni], acc[mi][ni], 0, 0, 0);                         \
        }                                                                        \
        __builtin_amdgcn_s_setprio(0);                                          \
    }
    // Entry: counted vmcnt (keeps next-tile B DMA + A loads in flight across the
    // barrier). Memory-clobber asm on both sides pins LDS-access ordering.
#define ENTRY_SYNC(N)                                                            \
    asm volatile("s_waitcnt vmcnt(" #N ")" ::: "memory");                        \
    __builtin_amdgcn_s_barrier();                                                \
    asm volatile("" ::: "memory");
    // Exit: own ds_writes must retire before signaling; VMEM stays in flight.
#define EXIT_SYNC()                                                              \
    asm volatile("s_waitcnt lgkmcnt(0)" ::: "memory");                           \
    __builtin_amdgcn_s_barrier();                                                \
    asm volatile("" ::: "memory");

    // ---- prologue: A0 -> regs -> LDS; B0 DMA; A1 in flight ----
    LOAD_A(asA, 0);
    ISSUE_B(0, 0);
    STAGE_A(0, asA);            // compiler waits on asA regs itself
    LOAD_A(asB, 1);
    asm volatile("s_waitcnt lgkmcnt(0)" ::: "memory");   // prologue ds_writes done

    // ---- steady loop: tiles 0..NT-3 (last pair peeled) ----
    // Per-wave VMEM FIFO at ENTRY (even iter tt): B(tt)[4] A(tt+1)[4] B(tt+1)[4]
    // A(tt+2)[4] = 16; vmcnt(8) retires exactly B(tt)+A(tt+1) (what COMPUTE and
    // STAGE_A need); B(tt+1)/A(tt+2) ride through the barrier.
    for (int tt = 0; tt + 3 < NT; tt += 2) {
        ISSUE_B(tt + 1, 1);
        LOAD_A(asA, tt + 2);
        ENTRY_SYNC(8)
        COMPUTE(0);
        STAGE_A(1, asB);
        EXIT_SYNC()

        ISSUE_B(tt + 2, 0);
        LOAD_A(asB, tt + 3);
        ENTRY_SYNC(8)
        COMPUTE(1);
        STAGE_A(0, asA);
        EXIT_SYNC()
    }

    // ---- peeled final pair (tiles NT-2, NT-1): no further A loads ----
    ISSUE_B(NT - 1, 1);
    ENTRY_SYNC(4)               // retires B(NT-2)+A(NT-1); B(NT-1) in flight
    COMPUTE(0);
    STAGE_A(1, asB);
    EXIT_SYNC()

    ENTRY_SYNC(0)               // drain B(NT-1)
    COMPUTE(1);

    // epilogue: tanh * v_w, reduce over this wave's 128 n-cols.
    // Slot = nchunk*2 + wn: exactly ONE writer per (slot,row) -> deterministic.
    float qb[8], vw[8];
#pragma unroll
    for (int ni = 0; ni < 8; ++ni) {
        int n = n0 + wn * 128 + ni * 16 + lr;
        qb[ni] = g_q[b * DM + n] + Wk_b[n];
        vw[ni] = v_w[n];
    }
#pragma unroll
    for (int mi = 0; mi < 4; ++mi) {
#pragma unroll
        for (int rg = 0; rg < 4; ++rg) {
            float p = 0.f;
#pragma unroll
            for (int ni = 0; ni < 8; ++ni) {
                float val = acc[mi][ni][rg] + qb[ni];
                p += tanh_fast(val) * vw[ni];
            }
#pragma unroll
            for (int off = 8; off >= 1; off >>= 1) p += __shfl_xor(p, off, 16);
            if (lr == 0)
                g_sp[nchunk * 2 + wn][m0 + wm * 64 + mi * 16 + lg * 4 + rg] = p;
        }
    }
#undef LOAD_A
#undef ISSUE_B
#undef STAGE_A
#undef COMPUTE
#undef ENTRY_SYNC
#undef EXIT_SYNC
}

// ---------------- softmax over S per batch row (sums the 8 partial slots) --------
__global__ __launch_bounds__(256) void softmax_kernel(float* __restrict__ attn) {
    int b = blockIdx.x;
    int tid = threadIdx.x;
    __shared__ float redm[4];
    __shared__ float reds[4];
    float v[8];
    float mx = -1e30f;
#pragma unroll
    for (int i = 0; i < 8; ++i) {
        int idx = b * SEQ + i * 256 + tid;
        float s = 0.f;
#pragma unroll
        for (int pslot = 0; pslot < 8; ++pslot) s += g_sp[pslot][idx];
        v[i] = s;
        mx = fmaxf(mx, v[i]);
    }
#pragma unroll
    for (int off = 32; off >= 1; off >>= 1) mx = fmaxf(mx, __shfl_xor(mx, off));
    int wid = tid >> 6;
    if ((tid & 63) == 0) redm[wid] = mx;
    __syncthreads();
    mx = fmaxf(fmaxf(redm[0], redm[1]), fmaxf(redm[2], redm[3]));
    float sum = 0.f;
#pragma unroll
    for (int i = 0; i < 8; ++i) {
        v[i] = expf(v[i] - mx);
        sum += v[i];
    }
#pragma unroll
    for (int off = 32; off >= 1; off >>= 1) sum += __shfl_xor(sum, off);
    if ((tid & 63) == 0) reds[wid] = sum;
    __syncthreads();
    sum = reds[0] + reds[1] + reds[2] + reds[3];
    float inv = 1.f / sum;
#pragma unroll
    for (int i = 0; i < 8; ++i) attn[b * SEQ + i * 256 + tid] = v[i] * inv;
}

// ---------------- context = attn @ keys (coalesced float4 rows) ----------------
__global__ __launch_bounds__(256) void context_kernel(const float* __restrict__ keys,
                                                      const float* __restrict__ attn,
                                                      float* __restrict__ context) {
    int id = blockIdx.x;              // 32 b x 16 schunk = 512 blocks
    int schunk = id & 15;
    int b = id >> 4;
    int tid = threadIdx.x;
    __shared__ float a_s[128];
    if (tid < 128) a_s[tid] = attn[b * SEQ + schunk * 128 + tid];
    __syncthreads();
    const float4* kp =
        reinterpret_cast<const float4*>(keys + ((size_t)b * SEQ + schunk * 128) * DM) + tid;
    float4 acc = {0.f, 0.f, 0.f, 0.f};
#pragma unroll 4
    for (int s = 0; s < 128; ++s) {
        float4 kv = kp[(size_t)s * (DM / 4)];
        float a = a_s[s];
        acc.x += a * kv.x; acc.y += a * kv.y; acc.z += a * kv.z; acc.w += a * kv.w;
    }
    atomicAdd(&context[b * DM + tid * 4 + 0], acc.x);
    atomicAdd(&context[b * DM + tid * 4 + 1], acc.y);
    atomicAdd(&context[b * DM + tid * 4 + 2], acc.z);
    atomicAdd(&context[b * DM + tid * 4 + 3], acc.w);
}

extern "C" void kernel_launch(void* const* d_in, const int* in_sizes, int n_in,
                              void* d_out, int out_size, void* d_ws, size_t ws_size,
                              hipStream_t stream) {
    const float* query = (const float*)d_in[0];
    const float* keys  = (const float*)d_in[1];
    const float* Wq_w  = (const float*)d_in[2];
    const float* Wq_b  = (const float*)d_in[3];
    const float* Wk_w  = (const float*)d_in[4];
    const float* Wk_b  = (const float*)d_in[5];
    const float* v_w   = (const float*)d_in[6];
    // d_in[7] = v_b: additive constant on all scores -> cancels exactly in softmax.

    float* context = (float*)d_out;              // [32][1024]
    float* attn    = context + BATCH * DM;       // [32][2048]

    hipLaunchKernelGGL(convb_kernel, dim3(1024), dim3(256), 0, stream, Wk_w);
    hipLaunchKernelGGL(init_kernel, dim3(128), dim3(256), 0, stream, context);
    hipLaunchKernelGGL(qproj_kernel, dim3(DM), dim3(256), 0, stream, query, Wq_w, Wq_b);
    hipLaunchKernelGGL(scores_kernel, dim3((BATCH * SEQ / BM) * (DM / BN)), dim3(256), 0, stream,
                       keys, Wk_b, v_w);
    hipLaunchKernelGGL(softmax_kernel, dim3(BATCH), dim3(256), 0, stream, attn);
    hipLaunchKernelGGL(context_kernel, dim3(512), dim3(256), 0, stream, keys, attn, context);
}

// Round 8
// 342.882 us; speedup vs baseline: 4.1985x; 4.1985x over previous
//
#include <hip/hip_runtime.h>
#include <cstddef>
#include <cstdint>

#define BATCH 32
#define SEQ 2048
#define DM 1024

typedef __attribute__((ext_vector_type(8))) _Float16 half8v;
typedef __attribute__((ext_vector_type(4))) _Float16 half4v;
typedef __attribute__((ext_vector_type(4))) float f32x4;

// Persistent device-global scratch (fully rewritten every launch; no stale-state deps)
__device__ _Float16 g_B16[DM * DM];            // Wk_w pre-converted to fp16 (2 MB)
__device__ float g_q[BATCH * DM];              // q projection (128 KB)
__device__ float g_sp[8][BATCH * SEQ];         // scores partials: slot = nchunk*2 + wn

// tanh(x) = 1 - 2/(e^{2x}+1); saturates to +-1 correctly for |x| large
__device__ __forceinline__ float tanh_fast(float x) {
    float e = __expf(2.0f * x);
    return 1.0f - 2.0f / (e + 1.0f);
}

__device__ __forceinline__ void gload16(const void* g, void* l) {
    __builtin_amdgcn_global_load_lds((__attribute__((address_space(1))) void*)g,
                                     (__attribute__((address_space(3))) void*)l, 16, 0, 0);
}

// ---------------- convert Wk_w -> fp16 (once per launch, ~6 MB traffic) ----------------
__global__ __launch_bounds__(256) void convb_kernel(const float* __restrict__ Wk_w) {
    int i = blockIdx.x * 256 + threadIdx.x;            // 262144 float4 groups
    float4 w = reinterpret_cast<const float4*>(Wk_w)[i];
    half4v h;
    h[0] = (_Float16)w.x; h[1] = (_Float16)w.y; h[2] = (_Float16)w.z; h[3] = (_Float16)w.w;
    *reinterpret_cast<half4v*>(&g_B16[(size_t)i * 4]) = h;
}

// ---------------- init: zero context (atomically accumulated) ----------------
__global__ __launch_bounds__(256) void init_kernel(float* __restrict__ context) {
    int idx = blockIdx.x * 256 + threadIdx.x;
    if (idx < BATCH * DM) context[idx] = 0.f;
}

// ---------------- q projection: block per output d; Wq read once total ----------------
__global__ __launch_bounds__(256) void qproj_kernel(const float* __restrict__ query,
                                                    const float* __restrict__ Wq_w,
                                                    const float* __restrict__ Wq_b) {
    int d = blockIdx.x;
    int t = threadIdx.x;
    __shared__ float wrow[DM];
    __shared__ float part[8][32];
    reinterpret_cast<float4*>(wrow)[t] =
        reinterpret_cast<const float4*>(Wq_w + (size_t)d * DM)[t];
    __syncthreads();
    int b = t & 31, seg = t >> 5;
    const float4* qp = reinterpret_cast<const float4*>(query + b * DM + seg * 128);
    const float4* wp = reinterpret_cast<const float4*>(wrow + seg * 128);
    float acc = 0.f;
#pragma unroll
    for (int i = 0; i < 32; ++i) {
        float4 qv = qp[i];
        float4 wv = wp[i];
        acc += qv.x * wv.x + qv.y * wv.y + qv.z * wv.z + qv.w * wv.w;
    }
    part[seg][b] = acc;
    __syncthreads();
    if (t < 32) {
        float s = Wq_b[d];
#pragma unroll
        for (int g = 0; g < 8; ++g) s += part[g][t];
        g_q[t * DM + d] = s;
    }
}

// ---------------- scores: single-pass fp16 MFMA GEMM, counted-vmcnt pipeline ----------
#define BM 128
#define BN 256
#define BK 32
#define NT (DM / BK)   // 32 K-steps

// NOTE: 2 waves/SIMD is the occupancy CEILING here: unified VGPR+AGPR need is
// ~240/lane (128 AGPR acc + ~112 VGPR). Requesting 3 (round 7) forced the
// compiler to spill the A-staging buffers -> 5.2 GB scratch traffic, 4.4x slower.
__global__ __launch_bounds__(256, 2) void scores_kernel(const float* __restrict__ keys,
                                                        const float* __restrict__ Wk_b,
                                                        const float* __restrict__ v_w) {
    // K-subtiled [buf][kc][row][8] fp16, 16B rows; B region layout matches the
    // linear lane x 16B pattern global_load_lds writes. Total 48 KB.
    __shared__ _Float16 AhS[2][4][BM][8];   // 16 KB
    __shared__ _Float16 BhS[2][4][BN][8];   // 32 KB

    // XCD-aware order: 2048 blocks = 8 XCDs x 256 slots (bijective); nchunk-minor
    // so the 4 blocks sharing an A-tile are co-resident on one XCD (A read once).
    const unsigned bid = blockIdx.x;
    const unsigned L = (bid & 7u) * 256u + (bid >> 3);
    const int mtile = (int)(L >> 2);       // 0..511
    const int nchunk = (int)(L & 3u);      // 0..3
    const int m0 = mtile * BM;
    const int n0 = nchunk * BN;
    const int b = m0 >> 11;

    const int t = threadIdx.x;
    const int w = t >> 6, l = t & 63;
    const int wm = w >> 1, wn = w & 1;     // 2x2 waves; wave tile 64m x 128n
    const int lr = l & 15, lg = l >> 4;

    // A staging: 2 threads/row, 16 k-elems each.
    const int ra = t >> 1, ha = t & 1;
    const float* Ap = keys + (size_t)(m0 + ra) * DM + ha * 16;

    float4 asA[4], asB[4];   // two A staging sets (pipeline depth 2 tiles)

    f32x4 acc[4][8];
#pragma unroll
    for (int mi = 0; mi < 4; ++mi)
#pragma unroll
        for (int ni = 0; ni < 8; ++ni)
#pragma unroll
            for (int c = 0; c < 4; ++c) acc[mi][ni][c] = 0.f;

#define LOAD_A(dst, kt)                                                          \
    {                                                                            \
        _Pragma("unroll") for (int j = 0; j < 4; ++j)                            \
            dst[j] = *reinterpret_cast<const float4*>(Ap + (kt) * BK + 4 * j);   \
    }
    // wave w DMAs kc=w plane: 4 issues x 64 rows x 16B
#define ISSUE_B(kt, bufi)                                                        \
    {                                                                            \
        const _Float16* gb = &g_B16[(size_t)(n0 + l) * DM + (kt) * BK + w * 8];  \
        _Pragma("unroll") for (int rg = 0; rg < 4; ++rg)                         \
            gload16(gb + (size_t)rg * 64 * DM, &BhS[bufi][w][rg * 64][0]);       \
    }
#define STAGE_A(bufi, aset)                                                      \
    {                                                                            \
        union H8 { _Float16 f[8]; half8v v; } ah[2];                             \
        _Pragma("unroll") for (int j = 0; j < 4; ++j) {                          \
            const float* fa = reinterpret_cast<const float*>(&aset[j]);          \
            _Pragma("unroll") for (int c = 0; c < 4; ++c) {                      \
                int idx = 4 * j + c;                                             \
                ah[idx >> 3].f[idx & 7] = (_Float16)fa[c];                       \
            }                                                                    \
        }                                                                        \
        *reinterpret_cast<half8v*>(&AhS[bufi][2 * ha][ra][0]) = ah[0].v;         \
        *reinterpret_cast<half8v*>(&AhS[bufi][2 * ha + 1][ra][0]) = ah[1].v;     \
    }
#define COMPUTE(bufi)                                                            \
    {                                                                            \
        half8v bhv[8];                                                           \
        _Pragma("unroll") for (int ni = 0; ni < 8; ++ni)                         \
            bhv[ni] = *reinterpret_cast<const half8v*>(                          \
                &BhS[bufi][lg][wn * 128 + ni * 16 + lr][0]);                     \
        __builtin_amdgcn_s_setprio(1);                                           \
        _Pragma("unroll") for (int mi = 0; mi < 4; ++mi) {                       \
            half8v ahv = *reinterpret_cast<const half8v*>(                       \
                &AhS[bufi][lg][wm * 64 + mi * 16 + lr][0]);                      \
            _Pragma("unroll") for (int ni = 0; ni < 8; ++ni)                     \
                acc[mi][ni] = __builtin_amdgcn_mfma_f32_16x16x32_f16(            \
                    ahv, bhv[ni], acc[mi][ni], 0, 0, 0);                         \
        }                                                                        \
        __builtin_amdgcn_s_setprio(0);                                          \
    }
    // Entry: counted vmcnt (keeps next-tile B DMA + A loads in flight across the
    // barrier). Memory-clobber asm on both sides pins LDS-access ordering.
#define ENTRY_SYNC(N)                                                            \
    asm volatile("s_waitcnt vmcnt(" #N ")" ::: "memory");                        \
    __builtin_amdgcn_s_barrier();                                                \
    asm volatile("" ::: "memory");
    // Exit: own ds_writes must retire before signaling; VMEM stays in flight.
#define EXIT_SYNC()                                                              \
    asm volatile("s_waitcnt lgkmcnt(0)" ::: "memory");                           \
    __builtin_amdgcn_s_barrier();                                                \
    asm volatile("" ::: "memory");

    // ---- prologue: A0 -> regs -> LDS; B0 DMA; A1 in flight ----
    LOAD_A(asA, 0);
    ISSUE_B(0, 0);
    STAGE_A(0, asA);            // compiler waits on asA regs itself
    LOAD_A(asB, 1);
    asm volatile("s_waitcnt lgkmcnt(0)" ::: "memory");   // prologue ds_writes done

    // ---- steady loop: tiles 0..NT-3 (last pair peeled) ----
    // Per-wave VMEM FIFO at ENTRY (even iter tt): B(tt)[4] A(tt+1)[4] B(tt+1)[4]
    // A(tt+2)[4] = 16; vmcnt(8) retires exactly B(tt)+A(tt+1) (what COMPUTE and
    // STAGE_A need); B(tt+1)/A(tt+2) ride through the barrier.
    for (int tt = 0; tt + 3 < NT; tt += 2) {
        ISSUE_B(tt + 1, 1);
        LOAD_A(asA, tt + 2);
        ENTRY_SYNC(8)
        COMPUTE(0);
        STAGE_A(1, asB);
        EXIT_SYNC()

        ISSUE_B(tt + 2, 0);
        LOAD_A(asB, tt + 3);
        ENTRY_SYNC(8)
        COMPUTE(1);
        STAGE_A(0, asA);
        EXIT_SYNC()
    }

    // ---- peeled final pair (tiles NT-2, NT-1): no further A loads ----
    ISSUE_B(NT - 1, 1);
    ENTRY_SYNC(4)               // retires B(NT-2)+A(NT-1); B(NT-1) in flight
    COMPUTE(0);
    STAGE_A(1, asB);
    EXIT_SYNC()

    ENTRY_SYNC(0)               // drain B(NT-1)
    COMPUTE(1);

    // epilogue: tanh * v_w, reduce over this wave's 128 n-cols.
    // Slot = nchunk*2 + wn: exactly ONE writer per (slot,row) -> deterministic.
    float qb[8], vw[8];
#pragma unroll
    for (int ni = 0; ni < 8; ++ni) {
        int n = n0 + wn * 128 + ni * 16 + lr;
        qb[ni] = g_q[b * DM + n] + Wk_b[n];
        vw[ni] = v_w[n];
    }
#pragma unroll
    for (int mi = 0; mi < 4; ++mi) {
#pragma unroll
        for (int rg = 0; rg < 4; ++rg) {
            float p = 0.f;
#pragma unroll
            for (int ni = 0; ni < 8; ++ni) {
                float val = acc[mi][ni][rg] + qb[ni];
                p += tanh_fast(val) * vw[ni];
            }
#pragma unroll
            for (int off = 8; off >= 1; off >>= 1) p += __shfl_xor(p, off, 16);
            if (lr == 0)
                g_sp[nchunk * 2 + wn][m0 + wm * 64 + mi * 16 + lg * 4 + rg] = p;
        }
    }
#undef LOAD_A
#undef ISSUE_B
#undef STAGE_A
#undef COMPUTE
#undef ENTRY_SYNC
#undef EXIT_SYNC
}

// ---------------- softmax over S per batch row (sums the 8 partial slots) --------
__global__ __launch_bounds__(256) void softmax_kernel(float* __restrict__ attn) {
    int b = blockIdx.x;
    int tid = threadIdx.x;
    __shared__ float redm[4];
    __shared__ float reds[4];
    float v[8];
    float mx = -1e30f;
#pragma unroll
    for (int i = 0; i < 8; ++i) {
        int idx = b * SEQ + i * 256 + tid;
        float s = 0.f;
#pragma unroll
        for (int pslot = 0; pslot < 8; ++pslot) s += g_sp[pslot][idx];
        v[i] = s;
        mx = fmaxf(mx, v[i]);
    }
#pragma unroll
    for (int off = 32; off >= 1; off >>= 1) mx = fmaxf(mx, __shfl_xor(mx, off));
    int wid = tid >> 6;
    if ((tid & 63) == 0) redm[wid] = mx;
    __syncthreads();
    mx = fmaxf(fmaxf(redm[0], redm[1]), fmaxf(redm[2], redm[3]));
    float sum = 0.f;
#pragma unroll
    for (int i = 0; i < 8; ++i) {
        v[i] = expf(v[i] - mx);
        sum += v[i];
    }
#pragma unroll
    for (int off = 32; off >= 1; off >>= 1) sum += __shfl_xor(sum, off);
    if ((tid & 63) == 0) reds[wid] = sum;
    __syncthreads();
    sum = reds[0] + reds[1] + reds[2] + reds[3];
    float inv = 1.f / sum;
#pragma unroll
    for (int i = 0; i < 8; ++i) attn[b * SEQ + i * 256 + tid] = v[i] * inv;
}

// ---------------- context = attn @ keys (coalesced float4 rows) ----------------
__global__ __launch_bounds__(256) void context_kernel(const float* __restrict__ keys,
                                                      const float* __restrict__ attn,
                                                      float* __restrict__ context) {
    int id = blockIdx.x;              // 32 b x 16 schunk = 512 blocks
    int schunk = id & 15;
    int b = id >> 4;
    int tid = threadIdx.x;
    __shared__ float a_s[128];
    if (tid < 128) a_s[tid] = attn[b * SEQ + schunk * 128 + tid];
    __syncthreads();
    const float4* kp =
        reinterpret_cast<const float4*>(keys + ((size_t)b * SEQ + schunk * 128) * DM) + tid;
    float4 acc = {0.f, 0.f, 0.f, 0.f};
#pragma unroll 4
    for (int s = 0; s < 128; ++s) {
        float4 kv = kp[(size_t)s * (DM / 4)];
        float a = a_s[s];
        acc.x += a * kv.x; acc.y += a * kv.y; acc.z += a * kv.z; acc.w += a * kv.w;
    }
    atomicAdd(&context[b * DM + tid * 4 + 0], acc.x);
    atomicAdd(&context[b * DM + tid * 4 + 1], acc.y);
    atomicAdd(&context[b * DM + tid * 4 + 2], acc.z);
    atomicAdd(&context[b * DM + tid * 4 + 3], acc.w);
}

extern "C" void kernel_launch(void* const* d_in, const int* in_sizes, int n_in,
                              void* d_out, int out_size, void* d_ws, size_t ws_size,
                              hipStream_t stream) {
    const float* query = (const float*)d_in[0];
    const float* keys  = (const float*)d_in[1];
    const float* Wq_w  = (const float*)d_in[2];
    const float* Wq_b  = (const float*)d_in[3];
    const float* Wk_w  = (const float*)d_in[4];
    const float* Wk_b  = (const float*)d_in[5];
    const float* v_w   = (const float*)d_in[6];
    // d_in[7] = v_b: additive constant on all scores -> cancels exactly in softmax.

    float* context = (float*)d_out;              // [32][1024]
    float* attn    = context + BATCH * DM;       // [32][2048]

    hipLaunchKernelGGL(convb_kernel, dim3(1024), dim3(256), 0, stream, Wk_w);
    hipLaunchKernelGGL(init_kernel, dim3(128), dim3(256), 0, stream, context);
    hipLaunchKernelGGL(qproj_kernel, dim3(DM), dim3(256), 0, stream, query, Wq_w, Wq_b);
    hipLaunchKernelGGL(scores_kernel, dim3((BATCH * SEQ / BM) * (DM / BN)), dim3(256), 0, stream,
                       keys, Wk_b, v_w);
    hipLaunchKernelGGL(softmax_kernel, dim3(BATCH), dim3(256), 0, stream, attn);
    hipLaunchKernelGGL(context_kernel, dim3(512), dim3(256), 0, stream, keys, attn, context);
}

// Round 9
// 270.347 us; speedup vs baseline: 5.3250x; 1.2683x over previous
//
#include <hip/hip_runtime.h>
#include <cstddef>
#include <cstdint>

#define BATCH 32
#define SEQ 2048
#define DM 1024

typedef __attribute__((ext_vector_type(8))) _Float16 half8v;
typedef __attribute__((ext_vector_type(4))) _Float16 half4v;
typedef __attribute__((ext_vector_type(4))) float f32x4;

// Persistent device-global scratch (fully rewritten every launch; no stale-state deps)
// g_Bpk: Wk_w pre-packed as the exact LDS image: [nchunk][kt][kc][row 256][8 halfs]
__device__ _Float16 g_Bpk[4 * 32 * 4 * 256 * 8];   // 2 MB
__device__ float g_q[BATCH * DM];                  // q projection (128 KB)
__device__ float g_sp[8][BATCH * SEQ];             // scores partials: slot = nchunk*2 + wn

// tanh(x) = 1 - 2/(e^{2x}+1); saturates to +-1 correctly for |x| large
__device__ __forceinline__ float tanh_fast(float x) {
    float e = __expf(2.0f * x);
    return 1.0f - 2.0f / (e + 1.0f);
}

__device__ __forceinline__ void gload16(const void* g, void* l) {
    __builtin_amdgcn_global_load_lds((__attribute__((address_space(1))) void*)g,
                                     (__attribute__((address_space(3))) void*)l, 16, 0, 0);
}

// ---------------- pack Wk_w -> fp16 LDS-image layout (once per launch) ----------------
// block = (nc, kt); thread t = row. Writes are 16B-stride coalesced; reads are
// divergent but one-time (~8 MB).
__global__ __launch_bounds__(256) void packb_kernel(const float* __restrict__ Wk_w) {
    int p = blockIdx.x;            // 0..127 = nc*32 + kt
    int nc = p >> 5, kt = p & 31;
    int t = threadIdx.x;           // row 0..255
    const float* src = Wk_w + (size_t)(nc * 256 + t) * DM + kt * 32;
#pragma unroll
    for (int kc = 0; kc < 4; ++kc) {
        float4 w0 = *reinterpret_cast<const float4*>(src + kc * 8);
        float4 w1 = *reinterpret_cast<const float4*>(src + kc * 8 + 4);
        union { _Float16 f[8]; half8v v; } h;
        h.f[0] = (_Float16)w0.x; h.f[1] = (_Float16)w0.y;
        h.f[2] = (_Float16)w0.z; h.f[3] = (_Float16)w0.w;
        h.f[4] = (_Float16)w1.x; h.f[5] = (_Float16)w1.y;
        h.f[6] = (_Float16)w1.z; h.f[7] = (_Float16)w1.w;
        *reinterpret_cast<half8v*>(
            &g_Bpk[((((size_t)p) * 4 + kc) * 256 + t) * 8]) = h.v;
    }
}

// ---------------- init: zero context (atomically accumulated) ----------------
__global__ __launch_bounds__(256) void init_kernel(float* __restrict__ context) {
    int idx = blockIdx.x * 256 + threadIdx.x;
    if (idx < BATCH * DM) context[idx] = 0.f;
}

// ---------------- q projection: block per output d; Wq read once total ----------------
__global__ __launch_bounds__(256) void qproj_kernel(const float* __restrict__ query,
                                                    const float* __restrict__ Wq_w,
                                                    const float* __restrict__ Wq_b) {
    int d = blockIdx.x;
    int t = threadIdx.x;
    __shared__ float wrow[DM];
    __shared__ float part[8][32];
    reinterpret_cast<float4*>(wrow)[t] =
        reinterpret_cast<const float4*>(Wq_w + (size_t)d * DM)[t];
    __syncthreads();
    int b = t & 31, seg = t >> 5;
    const float4* qp = reinterpret_cast<const float4*>(query + b * DM + seg * 128);
    const float4* wp = reinterpret_cast<const float4*>(wrow + seg * 128);
    float acc = 0.f;
#pragma unroll
    for (int i = 0; i < 32; ++i) {
        float4 qv = qp[i];
        float4 wv = wp[i];
        acc += qv.x * wv.x + qv.y * wv.y + qv.z * wv.z + qv.w * wv.w;
    }
    part[seg][b] = acc;
    __syncthreads();
    if (t < 32) {
        float s = Wq_b[d];
#pragma unroll
        for (int g = 0; g < 8; ++g) s += part[g][t];
        g_q[t * DM + d] = s;
    }
}

// ---------------- scores: single-pass fp16 MFMA GEMM, coalesced staging ----------
#define BM 128
#define BN 256
#define BK 32
#define NT (DM / BK)   // 32 K-steps

// 2 waves/SIMD is the occupancy ceiling (unified VGPR+AGPR ~244/lane).
__global__ __launch_bounds__(256, 2) void scores_kernel(const float* __restrict__ keys,
                                                        const float* __restrict__ Wk_b,
                                                        const float* __restrict__ v_w) {
    // A: kc-stride padded (129 rows) -> conflict-free ds_write_b64 staging.
    // B: EXACTLY linear [kc][256][8] (global_load_lds writes base + lane*16).
    __shared__ _Float16 AhS[2][4][BM + 1][8];   // ~16.5 KB
    __shared__ _Float16 BhS[2][4][BN][8];       // 32 KB

    // XCD-aware order: 2048 blocks = 8 XCDs x 256 slots (bijective); nchunk-minor
    // so the 4 blocks sharing an A-tile are co-resident on one XCD (A read once).
    const unsigned bid = blockIdx.x;
    const unsigned L = (bid & 7u) * 256u + (bid >> 3);
    const int mtile = (int)(L >> 2);       // 0..511
    const int nchunk = (int)(L & 3u);      // 0..3
    const int m0 = mtile * BM;
    const int n0 = nchunk * BN;
    const int b = m0 >> 11;

    const int t = threadIdx.x;
    const int w = t >> 6, l = t & 63;
    const int wm = w >> 1, wn = w & 1;     // 2x2 waves; wave tile 64m x 128n
    const int lr = l & 15, lg = l >> 4;

    // A staging: wave w owns rows w*32..w*32+31; inst j reads 8 full 128B rows
    // (lane -> row l>>3, col (l&7)*4): 8 contiguous segments per instruction.
    const int arow = w * 32 + (l >> 3);
    const int acol = (l & 7) * 4;          // 0,4,..,28
    const int akc = (l & 7) >> 1;          // 0..3
    const int aoff = ((l & 7) & 1) * 4;    // 0 or 4
    const float* Ap = keys + (size_t)(m0 + arow) * DM + acol;

    // B DMA: wave w fetches kc=w plane; lane l -> contiguous 16B at base + l*16.
    const _Float16* Bp = g_Bpk + ((((size_t)nchunk * 32) * 4 + w) * 256 + l) * 8;

    float4 asA[4], asB[4];   // two A staging sets (pipeline depth 2 tiles)

    f32x4 acc[4][8];
#pragma unroll
    for (int mi = 0; mi < 4; ++mi)
#pragma unroll
        for (int ni = 0; ni < 8; ++ni)
#pragma unroll
            for (int c = 0; c < 4; ++c) acc[mi][ni][c] = 0.f;

#define LOAD_A(dst, kt)                                                          \
    {                                                                            \
        _Pragma("unroll") for (int j = 0; j < 4; ++j)                            \
            dst[j] = *reinterpret_cast<const float4*>(                           \
                Ap + (size_t)j * 8 * DM + (kt) * BK);                            \
    }
    // wave w DMAs kc=w plane: 4 issues x (64 rows x 16B contiguous)
#define ISSUE_B(kt, bufi)                                                        \
    {                                                                            \
        const _Float16* gb = Bp + (size_t)(kt) * (4 * 256 * 8);                  \
        _Pragma("unroll") for (int rg = 0; rg < 4; ++rg)                         \
            gload16(gb + rg * 512, &BhS[bufi][w][rg * 64][0]);                   \
    }
#define STAGE_A(bufi, aset)                                                      \
    {                                                                            \
        _Pragma("unroll") for (int j = 0; j < 4; ++j) {                          \
            const float* fa = reinterpret_cast<const float*>(&aset[j]);          \
            union { _Float16 f[4]; half4v v; } h;                                \
            h.f[0] = (_Float16)fa[0]; h.f[1] = (_Float16)fa[1];                  \
            h.f[2] = (_Float16)fa[2]; h.f[3] = (_Float16)fa[3];                  \
            *reinterpret_cast<half4v*>(                                          \
                &AhS[bufi][akc][arow - w * 32 + w * 32 + j * 8][aoff]) = h.v;    \
        }                                                                        \
    }
#define COMPUTE(bufi)                                                            \
    {                                                                            \
        half8v bhv[8];                                                           \
        _Pragma("unroll") for (int ni = 0; ni < 8; ++ni)                         \
            bhv[ni] = *reinterpret_cast<const half8v*>(                          \
                &BhS[bufi][lg][wn * 128 + ni * 16 + lr][0]);                     \
        __builtin_amdgcn_s_setprio(1);                                           \
        _Pragma("unroll") for (int mi = 0; mi < 4; ++mi) {                       \
            half8v ahv = *reinterpret_cast<const half8v*>(                       \
                &AhS[bufi][lg][wm * 64 + mi * 16 + lr][0]);                      \
            _Pragma("unroll") for (int ni = 0; ni < 8; ++ni)                     \
                acc[mi][ni] = __builtin_amdgcn_mfma_f32_16x16x32_f16(            \
                    ahv, bhv[ni], acc[mi][ni], 0, 0, 0);                         \
        }                                                                        \
        __builtin_amdgcn_s_setprio(0);                                          \
    }
#define ENTRY_SYNC(N)                                                            \
    asm volatile("s_waitcnt vmcnt(" #N ")" ::: "memory");                        \
    __builtin_amdgcn_s_barrier();                                                \
    asm volatile("" ::: "memory");
#define EXIT_SYNC()                                                              \
    asm volatile("s_waitcnt lgkmcnt(0)" ::: "memory");                           \
    __builtin_amdgcn_s_barrier();                                                \
    asm volatile("" ::: "memory");

    // NOTE on STAGE_A row index: rows j*8 + (l>>3) within wave's 32-row band;
    // absolute row = w*32 + j*8 + (l>>3) = arow - (l>>3) + j*8 + (l>>3).
    // Written explicitly below via arow/j to keep indices compile-time static.

    // ---- prologue: A0 -> regs -> LDS; B0 DMA; A1 in flight ----
    LOAD_A(asA, 0);
    ISSUE_B(0, 0);
    {   // stage tile 0 (compiler inserts reg waits)
#pragma unroll
        for (int j = 0; j < 4; ++j) {
            const float* fa = reinterpret_cast<const float*>(&asA[j]);
            union { _Float16 f[4]; half4v v; } h;
            h.f[0] = (_Float16)fa[0]; h.f[1] = (_Float16)fa[1];
            h.f[2] = (_Float16)fa[2]; h.f[3] = (_Float16)fa[3];
            *reinterpret_cast<half4v*>(&AhS[0][akc][w * 32 + j * 8 + (l >> 3)][aoff]) = h.v;
        }
    }
    LOAD_A(asB, 1);
    asm volatile("s_waitcnt lgkmcnt(0)" ::: "memory");   // prologue ds_writes done

#undef STAGE_A
#define STAGE_A(bufi, aset)                                                      \
    {                                                                            \
        _Pragma("unroll") for (int j = 0; j < 4; ++j) {                          \
            const float* fa = reinterpret_cast<const float*>(&aset[j]);          \
            union { _Float16 f[4]; half4v v; } h;                                \
            h.f[0] = (_Float16)fa[0]; h.f[1] = (_Float16)fa[1];                  \
            h.f[2] = (_Float16)fa[2]; h.f[3] = (_Float16)fa[3];                  \
            *reinterpret_cast<half4v*>(                                          \
                &AhS[bufi][akc][w * 32 + j * 8 + (l >> 3)][aoff]) = h.v;         \
        }                                                                        \
    }

    // ---- steady loop: per-wave VMEM FIFO at ENTRY (iter tt): B(tt)[4] A(tt+1)[4]
    // B(tt+1)[4] A(tt+2)[4] = 16; vmcnt(8) retires exactly B(tt)+A(tt+1).
    for (int tt = 0; tt + 3 < NT; tt += 2) {
        ISSUE_B(tt + 1, 1);
        LOAD_A(asA, tt + 2);
        ENTRY_SYNC(8)
        COMPUTE(0);
        STAGE_A(1, asB);
        EXIT_SYNC()

        ISSUE_B(tt + 2, 0);
        LOAD_A(asB, tt + 3);
        ENTRY_SYNC(8)
        COMPUTE(1);
        STAGE_A(0, asA);
        EXIT_SYNC()
    }

    // ---- peeled final pair (tiles NT-2, NT-1) ----
    ISSUE_B(NT - 1, 1);
    ENTRY_SYNC(4)               // retires B(NT-2)+A(NT-1); B(NT-1) in flight
    COMPUTE(0);
    STAGE_A(1, asB);
    EXIT_SYNC()

    ENTRY_SYNC(0)               // drain B(NT-1)
    COMPUTE(1);

    // epilogue: tanh * v_w, reduce over this wave's 128 n-cols.
    // Slot = nchunk*2 + wn: exactly ONE writer per (slot,row) -> deterministic.
    float qb[8], vw[8];
#pragma unroll
    for (int ni = 0; ni < 8; ++ni) {
        int n = n0 + wn * 128 + ni * 16 + lr;
        qb[ni] = g_q[b * DM + n] + Wk_b[n];
        vw[ni] = v_w[n];
    }
#pragma unroll
    for (int mi = 0; mi < 4; ++mi) {
#pragma unroll
        for (int rg = 0; rg < 4; ++rg) {
            float p = 0.f;
#pragma unroll
            for (int ni = 0; ni < 8; ++ni) {
                float val = acc[mi][ni][rg] + qb[ni];
                p += tanh_fast(val) * vw[ni];
            }
#pragma unroll
            for (int off = 8; off >= 1; off >>= 1) p += __shfl_xor(p, off, 16);
            if (lr == 0)
                g_sp[nchunk * 2 + wn][m0 + wm * 64 + mi * 16 + lg * 4 + rg] = p;
        }
    }
#undef LOAD_A
#undef ISSUE_B
#undef STAGE_A
#undef COMPUTE
#undef ENTRY_SYNC
#undef EXIT_SYNC
}

// ---------------- softmax over S per batch row (sums the 8 partial slots) --------
__global__ __launch_bounds__(256) void softmax_kernel(float* __restrict__ attn) {
    int b = blockIdx.x;
    int tid = threadIdx.x;
    __shared__ float redm[4];
    __shared__ float reds[4];
    float v[8];
    float mx = -1e30f;
#pragma unroll
    for (int i = 0; i < 8; ++i) {
        int idx = b * SEQ + i * 256 + tid;
        float s = 0.f;
#pragma unroll
        for (int pslot = 0; pslot < 8; ++pslot) s += g_sp[pslot][idx];
        v[i] = s;
        mx = fmaxf(mx, v[i]);
    }
#pragma unroll
    for (int off = 32; off >= 1; off >>= 1) mx = fmaxf(mx, __shfl_xor(mx, off));
    int wid = tid >> 6;
    if ((tid & 63) == 0) redm[wid] = mx;
    __syncthreads();
    mx = fmaxf(fmaxf(redm[0], redm[1]), fmaxf(redm[2], redm[3]));
    float sum = 0.f;
#pragma unroll
    for (int i = 0; i < 8; ++i) {
        v[i] = expf(v[i] - mx);
        sum += v[i];
    }
#pragma unroll
    for (int off = 32; off >= 1; off >>= 1) sum += __shfl_xor(sum, off);
    if ((tid & 63) == 0) reds[wid] = sum;
    __syncthreads();
    sum = reds[0] + reds[1] + reds[2] + reds[3];
    float inv = 1.f / sum;
#pragma unroll
    for (int i = 0; i < 8; ++i) attn[b * SEQ + i * 256 + tid] = v[i] * inv;
}

// ---------------- context = attn @ keys (coalesced float4 rows) ----------------
__global__ __launch_bounds__(256) void context_kernel(const float* __restrict__ keys,
                                                      const float* __restrict__ attn,
                                                      float* __restrict__ context) {
    int id = blockIdx.x;              // 32 b x 16 schunk = 512 blocks
    int schunk = id & 15;
    int b = id >> 4;
    int tid = threadIdx.x;
    __shared__ float a_s[128];
    if (tid < 128) a_s[tid] = attn[b * SEQ + schunk * 128 + tid];
    __syncthreads();
    const float4* kp =
        reinterpret_cast<const float4*>(keys + ((size_t)b * SEQ + schunk * 128) * DM) + tid;
    float4 acc = {0.f, 0.f, 0.f, 0.f};
#pragma unroll 4
    for (int s = 0; s < 128; ++s) {
        float4 kv = kp[(size_t)s * (DM / 4)];
        float a = a_s[s];
        acc.x += a * kv.x; acc.y += a * kv.y; acc.z += a * kv.z; acc.w += a * kv.w;
    }
    atomicAdd(&context[b * DM + tid * 4 + 0], acc.x);
    atomicAdd(&context[b * DM + tid * 4 + 1], acc.y);
    atomicAdd(&context[b * DM + tid * 4 + 2], acc.z);
    atomicAdd(&context[b * DM + tid * 4 + 3], acc.w);
}

extern "C" void kernel_launch(void* const* d_in, const int* in_sizes, int n_in,
                              void* d_out, int out_size, void* d_ws, size_t ws_size,
                              hipStream_t stream) {
    const float* query = (const float*)d_in[0];
    const float* keys  = (const float*)d_in[1];
    const float* Wq_w  = (const float*)d_in[2];
    const float* Wq_b  = (const float*)d_in[3];
    const float* Wk_w  = (const float*)d_in[4];
    const float* Wk_b  = (const float*)d_in[5];
    const float* v_w   = (const float*)d_in[6];
    // d_in[7] = v_b: additive constant on all scores -> cancels exactly in softmax.

    float* context = (float*)d_out;              // [32][1024]
    float* attn    = context + BATCH * DM;       // [32][2048]

    hipLaunchKernelGGL(packb_kernel, dim3(128), dim3(256), 0, stream, Wk_w);
    hipLaunchKernelGGL(init_kernel, dim3(128), dim3(256), 0, stream, context);
    hipLaunchKernelGGL(qproj_kernel, dim3(DM), dim3(256), 0, stream, query, Wq_w, Wq_b);
    hipLaunchKernelGGL(scores_kernel, dim3((BATCH * SEQ / BM) * (DM / BN)), dim3(256), 0, stream,
                       keys, Wk_b, v_w);
    hipLaunchKernelGGL(softmax_kernel, dim3(BATCH), dim3(256), 0, stream, attn);
    hipLaunchKernelGGL(context_kernel, dim3(512), dim3(256), 0, stream, keys, attn, context);
}